// Round 1
// baseline (960.190 us; speedup 1.0000x reference)
//
#include <hip/hip_runtime.h>

#define BATCH 2
#define SEQL  2048
#define NEMB  1024
#define NH    16
#define HD    64
#define MROWS (BATCH*SEQL)   // 4096

// ---------------------------------------------------------------------------
// Kernel 1: QKV projection.  Q/K/V[b,h,t,d] = sum_c ix[b,t,c] * W[h,c,d]
// GEMM: M=4096 (b*T+t), K=1024 (c), N=1024 (h*64+d); grid.z picks Q/K/V.
// 128x128 tile, BK=16, 256 threads, 8x8 per thread (rows/cols split 4+4).
// ---------------------------------------------------------------------------
__global__ __launch_bounds__(256) void qkv_proj_kernel(
    const float* __restrict__ ix,
    const float* __restrict__ Wq, const float* __restrict__ Wk, const float* __restrict__ Wv,
    float* __restrict__ Qo, float* __restrict__ Ko, float* __restrict__ Vo)
{
    const int m0 = blockIdx.x * 128;
    const int n0 = blockIdx.y * 128;
    const int z  = blockIdx.z;
    const float* __restrict__ W  = (z == 0) ? Wq : (z == 1) ? Wk : Wv;
    float* __restrict__ Out      = (z == 0) ? Qo : (z == 1) ? Ko : Vo;

    __shared__ float a_t[16][132];   // A tile transposed: [k][row], pad->132
    __shared__ float b_s[16][132];   // B tile: [k][col]

    const int tid = threadIdx.x;
    const int ty = tid >> 4, tx = tid & 15;

    float acc[8][8] = {};

    for (int k0 = 0; k0 < NEMB; k0 += 16) {
        // stage A (ix): 128 rows x 16 k = 512 float4, 2 per thread
        #pragma unroll
        for (int q = 0; q < 2; ++q) {
            int fidx = q * 256 + tid;
            int row  = fidx >> 2;      // 0..127
            int kq   = fidx & 3;       // float4 index along k
            float4 v = *(const float4*)(ix + (m0 + row) * NEMB + k0 + kq * 4);
            a_t[kq*4+0][row] = v.x;
            a_t[kq*4+1][row] = v.y;
            a_t[kq*4+2][row] = v.z;
            a_t[kq*4+3][row] = v.w;
        }
        // stage B (W[h][c][d], n = h*64+d): 16 k x 128 n = 512 float4
        #pragma unroll
        for (int q = 0; q < 2; ++q) {
            int fidx = q * 256 + tid;
            int kk = fidx >> 5;
            int nn = (fidx & 31) * 4;
            int n  = n0 + nn;
            float4 v = *(const float4*)(W + (n >> 6) * (NEMB * HD) + (k0 + kk) * HD + (n & 63));
            *(float4*)(&b_s[kk][nn]) = v;
        }
        __syncthreads();
        #pragma unroll
        for (int kk = 0; kk < 16; ++kk) {
            float a[8], b[8];
            *(float4*)&a[0] = *(const float4*)&a_t[kk][ty * 4];
            *(float4*)&a[4] = *(const float4*)&a_t[kk][64 + ty * 4];
            *(float4*)&b[0] = *(const float4*)&b_s[kk][tx * 4];
            *(float4*)&b[4] = *(const float4*)&b_s[kk][64 + tx * 4];
            #pragma unroll
            for (int i = 0; i < 8; ++i)
                #pragma unroll
                for (int j = 0; j < 8; ++j)
                    acc[i][j] = fmaf(a[i], b[j], acc[i][j]);
        }
        __syncthreads();
    }
    // write out to [B,H,T,D] layout
    #pragma unroll
    for (int ih = 0; ih < 2; ++ih) {
        #pragma unroll
        for (int i2 = 0; i2 < 4; ++i2) {
            int i  = ih * 4 + i2;
            int m  = m0 + ih * 64 + ty * 4 + i2;
            int bb = m >> 11;            // / 2048
            int t  = m & (SEQL - 1);
            #pragma unroll
            for (int jh = 0; jh < 2; ++jh) {
                int n = n0 + jh * 64 + tx * 4;
                int h = n >> 6, d = n & 63;
                float* dst = Out + ((bb * NH + h) * SEQL + t) * HD + d;
                *(float4*)dst = *(float4*)&acc[i][jh * 4];
            }
        }
    }
}

// ---------------------------------------------------------------------------
// Kernel 2: causal flash attention, fp32.
// One block = 64 Q-rows of one (b,h). 256 threads: thread (ty,tx) owns
// S rows 4ty+i, S cols 4tx+j, and O rows 4ty+i, O dims 4tx+j.
// Q/K/P tiles XOR-swizzled in LDS (col4-group ^= row>>2) for conflict-free
// float4 reads along d/s.  scores *= sqrt(C)=32 per the reference.
// ---------------------------------------------------------------------------
__global__ __launch_bounds__(256) void attn_kernel(
    const float* __restrict__ Q, const float* __restrict__ K, const float* __restrict__ V,
    float* __restrict__ AO)
{
    const int rb = blockIdx.x;      // row block (0..31)
    const int bh = blockIdx.y;      // b*NH + h (0..31)
    const int bb = bh >> 4;
    const int h  = bh & 15;

    __shared__ float q_s[64][64];
    __shared__ float k_s[64][64];
    __shared__ float v_s[64][64];
    __shared__ float p_s[64][64];

    const int tid = threadIdx.x;
    const int ty = tid >> 4, tx = tid & 15;

    const float* __restrict__ Qb = Q + ((size_t)bh * SEQL + rb * 64) * HD;
    const float* __restrict__ Kb = K + (size_t)bh * SEQL * HD;
    const float* __restrict__ Vb = V + (size_t)bh * SEQL * HD;

    // stage Q tile, swizzled
    #pragma unroll
    for (int q = 0; q < 4; ++q) {
        int fidx = q * 256 + tid;     // 1024 float4
        int r  = fidx >> 4;
        int dg = fidx & 15;
        float4 v = *(const float4*)(Qb + r * HD + dg * 4);
        int cg = dg ^ ((r >> 2) & 7);
        *(float4*)&q_s[r][cg * 4] = v;
    }

    float o[4][4] = {};
    float m_i[4], l_i[4];
    #pragma unroll
    for (int i = 0; i < 4; ++i) { m_i[i] = -1e30f; l_i[i] = 0.f; }

    for (int cb = 0; cb <= rb; ++cb) {
        // stage K (swizzled) and V (natural)
        #pragma unroll
        for (int q = 0; q < 4; ++q) {
            int fidx = q * 256 + tid;
            int s  = fidx >> 4;
            int dg = fidx & 15;
            float4 vk = *(const float4*)(Kb + (size_t)(cb * 64 + s) * HD + dg * 4);
            int cg = dg ^ ((s >> 2) & 7);
            *(float4*)&k_s[s][cg * 4] = vk;
            float4 vv = *(const float4*)(Vb + (size_t)(cb * 64 + s) * HD + dg * 4);
            *(float4*)&v_s[s][dg * 4] = vv;
        }
        __syncthreads();

        // S tile (4x4 per thread)
        float st[4][4] = {};
        #pragma unroll 8
        for (int d0 = 0; d0 < 64; d0 += 4) {
            int dg = d0 >> 2;
            float4 qv[4], kv[4];
            #pragma unroll
            for (int i = 0; i < 4; ++i) qv[i] = *(const float4*)&q_s[ty * 4 + i][(dg ^ (ty & 7)) * 4];
            #pragma unroll
            for (int j = 0; j < 4; ++j) kv[j] = *(const float4*)&k_s[tx * 4 + j][(dg ^ (tx & 7)) * 4];
            #pragma unroll
            for (int i = 0; i < 4; ++i)
                #pragma unroll
                for (int j = 0; j < 4; ++j) {
                    st[i][j] = fmaf(qv[i].x, kv[j].x, st[i][j]);
                    st[i][j] = fmaf(qv[i].y, kv[j].y, st[i][j]);
                    st[i][j] = fmaf(qv[i].z, kv[j].z, st[i][j]);
                    st[i][j] = fmaf(qv[i].w, kv[j].w, st[i][j]);
                }
        }
        // scale by sqrt(C)=32 and causal-mask the diagonal block
        #pragma unroll
        for (int i = 0; i < 4; ++i)
            #pragma unroll
            for (int j = 0; j < 4; ++j) {
                float sv = st[i][j] * 32.0f;
                if (cb == rb && (tx * 4 + j) > (ty * 4 + i)) sv = -1e30f;
                st[i][j] = sv;
            }

        // row max across the 16 tx lanes
        float mb[4];
        #pragma unroll
        for (int i = 0; i < 4; ++i)
            mb[i] = fmaxf(fmaxf(st[i][0], st[i][1]), fmaxf(st[i][2], st[i][3]));
        #pragma unroll
        for (int off = 1; off < 16; off <<= 1)
            #pragma unroll
            for (int i = 0; i < 4; ++i)
                mb[i] = fmaxf(mb[i], __shfl_xor(mb[i], off));

        float al[4];
        #pragma unroll
        for (int i = 0; i < 4; ++i) {
            float mnew = fmaxf(m_i[i], mb[i]);
            al[i] = __expf(m_i[i] - mnew);
            m_i[i] = mnew;
        }
        float rs[4] = {};
        #pragma unroll
        for (int i = 0; i < 4; ++i)
            #pragma unroll
            for (int j = 0; j < 4; ++j) {
                float p = __expf(st[i][j] - m_i[i]);
                st[i][j] = p;
                rs[i] += p;
            }
        #pragma unroll
        for (int off = 1; off < 16; off <<= 1)
            #pragma unroll
            for (int i = 0; i < 4; ++i)
                rs[i] += __shfl_xor(rs[i], off);
        #pragma unroll
        for (int i = 0; i < 4; ++i) {
            l_i[i] = l_i[i] * al[i] + rs[i];
            #pragma unroll
            for (int j = 0; j < 4; ++j) o[i][j] *= al[i];
        }

        // write P (swizzled)
        #pragma unroll
        for (int i = 0; i < 4; ++i) {
            float4 pv = make_float4(st[i][0], st[i][1], st[i][2], st[i][3]);
            *(float4*)&p_s[ty * 4 + i][(tx ^ (ty & 7)) * 4] = pv;
        }
        __syncthreads();

        // O += P * V
        #pragma unroll 8
        for (int s0 = 0; s0 < 64; s0 += 4) {
            int sg = s0 >> 2;
            float4 pv[4], vv[4];
            #pragma unroll
            for (int i = 0; i < 4; ++i) pv[i] = *(const float4*)&p_s[ty * 4 + i][(sg ^ (ty & 7)) * 4];
            #pragma unroll
            for (int k = 0; k < 4; ++k) vv[k] = *(const float4*)&v_s[s0 + k][tx * 4];
            #pragma unroll
            for (int i = 0; i < 4; ++i) {
                float4 p4 = pv[i];
                o[i][0] = fmaf(p4.x, vv[0].x, o[i][0]);
                o[i][1] = fmaf(p4.x, vv[0].y, o[i][1]);
                o[i][2] = fmaf(p4.x, vv[0].z, o[i][2]);
                o[i][3] = fmaf(p4.x, vv[0].w, o[i][3]);
                o[i][0] = fmaf(p4.y, vv[1].x, o[i][0]);
                o[i][1] = fmaf(p4.y, vv[1].y, o[i][1]);
                o[i][2] = fmaf(p4.y, vv[1].z, o[i][2]);
                o[i][3] = fmaf(p4.y, vv[1].w, o[i][3]);
                o[i][0] = fmaf(p4.z, vv[2].x, o[i][0]);
                o[i][1] = fmaf(p4.z, vv[2].y, o[i][1]);
                o[i][2] = fmaf(p4.z, vv[2].z, o[i][2]);
                o[i][3] = fmaf(p4.z, vv[2].w, o[i][3]);
                o[i][0] = fmaf(p4.w, vv[3].x, o[i][0]);
                o[i][1] = fmaf(p4.w, vv[3].y, o[i][1]);
                o[i][2] = fmaf(p4.w, vv[3].z, o[i][2]);
                o[i][3] = fmaf(p4.w, vv[3].w, o[i][3]);
            }
        }
        __syncthreads();
    }

    // epilogue: normalize and write attn_out[b, t, h*64+d]
    #pragma unroll
    for (int i = 0; i < 4; ++i) {
        float inv = 1.0f / l_i[i];
        int t = rb * 64 + ty * 4 + i;
        float4 ov = make_float4(o[i][0] * inv, o[i][1] * inv, o[i][2] * inv, o[i][3] * inv);
        *(float4*)(AO + ((size_t)(bb * SEQL + t)) * NEMB + h * HD + tx * 4) = ov;
    }
}

// ---------------------------------------------------------------------------
// Kernel 3: output projection + bias.  out[m][n] = sum_c A[m][c]*Wp[c][n] + bp[n]
// Same GEMM skeleton as kernel 1.
// ---------------------------------------------------------------------------
__global__ __launch_bounds__(256) void out_proj_kernel(
    const float* __restrict__ A,
    const float* __restrict__ Wp,
    const float* __restrict__ bp,
    float* __restrict__ out)
{
    const int m0 = blockIdx.x * 128;
    const int n0 = blockIdx.y * 128;

    __shared__ float a_t[16][132];
    __shared__ float b_s[16][132];

    const int tid = threadIdx.x;
    const int ty = tid >> 4, tx = tid & 15;

    float acc[8][8] = {};

    for (int k0 = 0; k0 < NEMB; k0 += 16) {
        #pragma unroll
        for (int q = 0; q < 2; ++q) {
            int fidx = q * 256 + tid;
            int row  = fidx >> 2;
            int kq   = fidx & 3;
            float4 v = *(const float4*)(A + (m0 + row) * NEMB + k0 + kq * 4);
            a_t[kq*4+0][row] = v.x;
            a_t[kq*4+1][row] = v.y;
            a_t[kq*4+2][row] = v.z;
            a_t[kq*4+3][row] = v.w;
        }
        #pragma unroll
        for (int q = 0; q < 2; ++q) {
            int fidx = q * 256 + tid;
            int kk = fidx >> 5;
            int nn = (fidx & 31) * 4;
            float4 v = *(const float4*)(Wp + (k0 + kk) * NEMB + n0 + nn);
            *(float4*)(&b_s[kk][nn]) = v;
        }
        __syncthreads();
        #pragma unroll
        for (int kk = 0; kk < 16; ++kk) {
            float a[8], b[8];
            *(float4*)&a[0] = *(const float4*)&a_t[kk][ty * 4];
            *(float4*)&a[4] = *(const float4*)&a_t[kk][64 + ty * 4];
            *(float4*)&b[0] = *(const float4*)&b_s[kk][tx * 4];
            *(float4*)&b[4] = *(const float4*)&b_s[kk][64 + tx * 4];
            #pragma unroll
            for (int i = 0; i < 8; ++i)
                #pragma unroll
                for (int j = 0; j < 8; ++j)
                    acc[i][j] = fmaf(a[i], b[j], acc[i][j]);
        }
        __syncthreads();
    }

    float4 bias[2];
    bias[0] = *(const float4*)(bp + n0 + tx * 4);
    bias[1] = *(const float4*)(bp + n0 + 64 + tx * 4);

    #pragma unroll
    for (int ih = 0; ih < 2; ++ih) {
        #pragma unroll
        for (int i2 = 0; i2 < 4; ++i2) {
            int i = ih * 4 + i2;
            int m = m0 + ih * 64 + ty * 4 + i2;
            #pragma unroll
            for (int jh = 0; jh < 2; ++jh) {
                float4 r;
                r.x = acc[i][jh*4+0] + ((const float*)&bias[jh])[0];
                r.y = acc[i][jh*4+1] + ((const float*)&bias[jh])[1];
                r.z = acc[i][jh*4+2] + ((const float*)&bias[jh])[2];
                r.w = acc[i][jh*4+3] + ((const float*)&bias[jh])[3];
                *(float4*)(out + (size_t)m * NEMB + n0 + jh * 64 + tx * 4) = r;
            }
        }
    }
}

// ---------------------------------------------------------------------------
extern "C" void kernel_launch(void* const* d_in, const int* in_sizes, int n_in,
                              void* d_out, int out_size, void* d_ws, size_t ws_size,
                              hipStream_t stream)
{
    const float* ix = (const float*)d_in[0];
    const float* Wq = (const float*)d_in[1];
    const float* Wk = (const float*)d_in[2];
    const float* Wv = (const float*)d_in[3];
    const float* Wp = (const float*)d_in[4];
    const float* bp = (const float*)d_in[5];
    float* out = (float*)d_out;

    const size_t NQ = (size_t)BATCH * NH * SEQL * HD;   // 4,194,304 elements
    float* Qw = (float*)d_ws;        // [B,H,T,D]
    float* Kw = Qw + NQ;
    float* Vw = Kw + NQ;
    float* AO = Vw + NQ;             // [B*T, NEMB]  (ws total: 64 MB)

    dim3 g1(MROWS / 128, NEMB / 128, 3);
    qkv_proj_kernel<<<g1, 256, 0, stream>>>(ix, Wq, Wk, Wv, Qw, Kw, Vw);

    dim3 g2(SEQL / 64, BATCH * NH);
    attn_kernel<<<g2, 256, 0, stream>>>(Qw, Kw, Vw, AO);

    dim3 g3(MROWS / 128, NEMB / 128);
    out_proj_kernel<<<g3, 256, 0, stream>>>(AO, Wp, bp, out);
}

// Round 2
// 590.391 us; speedup vs baseline: 1.6264x; 1.6264x over previous
//
#include <hip/hip_runtime.h>

#define BATCH 2
#define SEQL  2048
#define NEMB  1024
#define NH    16
#define HD    64
#define MROWS (BATCH*SEQL)   // 4096

typedef short bf16x8 __attribute__((ext_vector_type(8)));
typedef float f32x16 __attribute__((ext_vector_type(16)));

// round-to-nearest-even float -> bf16 bits
__device__ __forceinline__ unsigned short f2bf(float x) {
    union { float f; unsigned u; } v; v.f = x;
    unsigned r = v.u + 0x7FFFu + ((v.u >> 16) & 1u);
    return (unsigned short)(r >> 16);
}
__device__ __forceinline__ void split_bf16(float x, unsigned short& hi, unsigned short& lo) {
    hi = f2bf(x);
    union { unsigned u; float f; } h; h.u = ((unsigned)hi) << 16;
    lo = f2bf(x - h.f);
}

// ---------------------------------------------------------------------------
// Kernel 1: QKV projection (fp32 VALU GEMM, unchanged from round 1).
// ---------------------------------------------------------------------------
__global__ __launch_bounds__(256) void qkv_proj_kernel(
    const float* __restrict__ ix,
    const float* __restrict__ Wq, const float* __restrict__ Wk, const float* __restrict__ Wv,
    float* __restrict__ Qo, float* __restrict__ Ko, float* __restrict__ Vo)
{
    const int m0 = blockIdx.x * 128;
    const int n0 = blockIdx.y * 128;
    const int z  = blockIdx.z;
    const float* __restrict__ W  = (z == 0) ? Wq : (z == 1) ? Wk : Wv;
    float* __restrict__ Out      = (z == 0) ? Qo : (z == 1) ? Ko : Vo;

    __shared__ float a_t[16][132];
    __shared__ float b_s[16][132];

    const int tid = threadIdx.x;
    const int ty = tid >> 4, tx = tid & 15;

    float acc[8][8] = {};

    for (int k0 = 0; k0 < NEMB; k0 += 16) {
        #pragma unroll
        for (int q = 0; q < 2; ++q) {
            int fidx = q * 256 + tid;
            int row  = fidx >> 2;
            int kq   = fidx & 3;
            float4 v = *(const float4*)(ix + (m0 + row) * NEMB + k0 + kq * 4);
            a_t[kq*4+0][row] = v.x;
            a_t[kq*4+1][row] = v.y;
            a_t[kq*4+2][row] = v.z;
            a_t[kq*4+3][row] = v.w;
        }
        #pragma unroll
        for (int q = 0; q < 2; ++q) {
            int fidx = q * 256 + tid;
            int kk = fidx >> 5;
            int nn = (fidx & 31) * 4;
            int n  = n0 + nn;
            float4 v = *(const float4*)(W + (n >> 6) * (NEMB * HD) + (k0 + kk) * HD + (n & 63));
            *(float4*)(&b_s[kk][nn]) = v;
        }
        __syncthreads();
        #pragma unroll
        for (int kk = 0; kk < 16; ++kk) {
            float a[8], b[8];
            *(float4*)&a[0] = *(const float4*)&a_t[kk][ty * 4];
            *(float4*)&a[4] = *(const float4*)&a_t[kk][64 + ty * 4];
            *(float4*)&b[0] = *(const float4*)&b_s[kk][tx * 4];
            *(float4*)&b[4] = *(const float4*)&b_s[kk][64 + tx * 4];
            #pragma unroll
            for (int i = 0; i < 8; ++i)
                #pragma unroll
                for (int j = 0; j < 8; ++j)
                    acc[i][j] = fmaf(a[i], b[j], acc[i][j]);
        }
        __syncthreads();
    }
    #pragma unroll
    for (int ih = 0; ih < 2; ++ih) {
        #pragma unroll
        for (int i2 = 0; i2 < 4; ++i2) {
            int i  = ih * 4 + i2;
            int m  = m0 + ih * 64 + ty * 4 + i2;
            int bb = m >> 11;
            int t  = m & (SEQL - 1);
            #pragma unroll
            for (int jh = 0; jh < 2; ++jh) {
                int n = n0 + jh * 64 + tx * 4;
                int h = n >> 6, d = n & 63;
                float* dst = Out + ((bb * NH + h) * SEQL + t) * HD + d;
                *(float4*)dst = *(float4*)&acc[i][jh * 4];
            }
        }
    }
}

// ---------------------------------------------------------------------------
// Kernel 2: causal flash attention via MFMA (32x32x16 bf16).
// 4 waves/block; wave owns 32 q-rows; KV tiles of 64.
// QK^T swapped (A=K, B=Q) -> S^T: lane owns one q col (q = lane&31),
// 16 s-rows per lane-half.  Split-bf16 QK (3 MFMA) for fp32-grade scores.
// K(hi/lo) and V^T staged in LDS in fragment-linear order (conflict-free
// ds_read_b128).  P^T frags assembled in-register via pack + shfl_xor(32).
// O^T accumulator: col=q (matches lane's q), rows=d -> per-lane rescale.
// ---------------------------------------------------------------------------
__global__ __launch_bounds__(256) void attn_mfma_kernel(
    const float* __restrict__ Q, const float* __restrict__ K, const float* __restrict__ V,
    float* __restrict__ AO)
{
    __shared__ unsigned short khi_s[4096];   // [sblk2][chunk4][lane64][8]
    __shared__ unsigned short klo_s[4096];
    __shared__ unsigned short vt_s [4096];   // [dtile2][schunk4][lane64][8]

    // XCD-chunked swizzle: 64 consecutive swz ids (= 4 full heads) per XCD.
    const int bid  = blockIdx.x;                 // 0..511
    const int swz  = (bid & 7) * 64 + (bid >> 3);
    const int bh   = swz >> 4;                   // head id: b*NH+h
    const int rb   = 15 - (swz & 15);            // heavy blocks first

    const int tid  = threadIdx.x;
    const int wid  = tid >> 6;
    const int lane = tid & 63;
    const int ln   = lane & 31;                  // q col within wave tile
    const int h    = lane >> 5;                  // lane half

    const int qb     = rb * 128 + wid * 32;
    const int qglob  = qb + ln;

    const float* __restrict__ Qb = Q + (size_t)bh * SEQL * HD;
    const float* __restrict__ Kb = K + (size_t)bh * SEQL * HD;
    const float* __restrict__ Vb = V + (size_t)bh * SEQL * HD;

    // Q fragments (B operand): lane holds Q[qglob][c*16 + 8h + j], j=0..7
    bf16x8 qhi[4], qlo[4];
    #pragma unroll
    for (int c = 0; c < 4; ++c) {
        const float* qp = Qb + (size_t)qglob * HD + c * 16 + h * 8;
        #pragma unroll
        for (int j = 0; j < 8; ++j) {
            unsigned short hi_, lo_;
            split_bf16(qp[j], hi_, lo_);
            qhi[c][j] = (short)hi_;
            qlo[c][j] = (short)lo_;
        }
    }

    f32x16 oacc[2] = {};     // O^T, dtile 0/1: row=d (within tile), col=q
    float m_run = -1e30f, l_run = 0.f;

    const int ntiles    = 2 * (rb + 1);
    const int wave_qmax = qb + 31;

    for (int t = 0; t < ntiles; ++t) {
        const int s0 = t * 64;

        __syncthreads();   // previous tile's LDS reads done
        // ---- stage K (hi/lo) and V^T, fragment-linear ----
        #pragma unroll
        for (int qq = 0; qq < 4; ++qq) {
            int fidx = qq * 256 + tid;      // 0..1023 float4s
            int s  = fidx >> 4;             // 0..63
            int d0 = (fidx & 15) * 4;       // 0..60
            float4 kv = *(const float4*)(Kb + (size_t)(s0 + s) * HD + d0);
            int sblk  = s >> 5;
            int chunk = d0 >> 4;
            int lk    = (s & 31) + 32 * ((d0 >> 3) & 1);
            int ebase = ((sblk * 4 + chunk) * 64 + lk) * 8 + (d0 & 7);
            unsigned short h0,l0,h1,l1,h2,l2,h3,l3;
            split_bf16(kv.x, h0, l0); split_bf16(kv.y, h1, l1);
            split_bf16(kv.z, h2, l2); split_bf16(kv.w, h3, l3);
            uint2 ph, pl;
            ph.x = (unsigned)h0 | ((unsigned)h1 << 16);
            ph.y = (unsigned)h2 | ((unsigned)h3 << 16);
            pl.x = (unsigned)l0 | ((unsigned)l1 << 16);
            pl.y = (unsigned)l2 | ((unsigned)l3 << 16);
            *(uint2*)(khi_s + ebase) = ph;
            *(uint2*)(klo_s + ebase) = pl;

            float4 vv = *(const float4*)(Vb + (size_t)(s0 + s) * HD + d0);
            int dtile  = d0 >> 5;
            int schunk = s >> 4;
            int vbase  = ((dtile * 4 + schunk) * 64) * 8 + (s & 7);
            int lv0    = (d0 & 31) + 32 * ((s >> 3) & 1);
            vt_s[vbase + (lv0 + 0) * 8] = f2bf(vv.x);
            vt_s[vbase + (lv0 + 1) * 8] = f2bf(vv.y);
            vt_s[vbase + (lv0 + 2) * 8] = f2bf(vv.z);
            vt_s[vbase + (lv0 + 3) * 8] = f2bf(vv.w);
        }
        __syncthreads();

        if (s0 > wave_qmax) continue;   // wave-uniform; barriers stay matched

        const bf16x8* khf = (const bf16x8*)khi_s;
        const bf16x8* klf = (const bf16x8*)klo_s;
        const bf16x8* vtf = (const bf16x8*)vt_s;

        // ---- QK^T (split bf16, 3 MFMA per 16-d chunk) ----
        f32x16 sacc[2] = {};
        #pragma unroll
        for (int sb = 0; sb < 2; ++sb) {
            #pragma unroll
            for (int c = 0; c < 4; ++c) {
                bf16x8 ah = khf[(sb * 4 + c) * 64 + lane];
                bf16x8 al = klf[(sb * 4 + c) * 64 + lane];
                sacc[sb] = __builtin_amdgcn_mfma_f32_32x32x16_bf16(ah, qhi[c], sacc[sb], 0, 0, 0);
                sacc[sb] = __builtin_amdgcn_mfma_f32_32x32x16_bf16(ah, qlo[c], sacc[sb], 0, 0, 0);
                sacc[sb] = __builtin_amdgcn_mfma_f32_32x32x16_bf16(al, qhi[c], sacc[sb], 0, 0, 0);
            }
        }

        // ---- scale *32, causal mask, online softmax ----
        const bool diag = (s0 + 63) > qb;   // tile not fully visible for min q
        float mtile = -1e30f;
        #pragma unroll
        for (int sb = 0; sb < 2; ++sb) {
            #pragma unroll
            for (int r = 0; r < 16; ++r) {
                int srow = (r & 3) + 8 * (r >> 2) + 4 * h + sb * 32;
                float x = sacc[sb][r] * 32.0f;
                if (diag && (s0 + srow) > qglob) x = -1e30f;
                sacc[sb][r] = x;
                mtile = fmaxf(mtile, x);
            }
        }
        mtile = fmaxf(mtile, __shfl_xor(mtile, 32));
        const float mnew  = fmaxf(m_run, mtile);
        const float alpha = __expf(m_run - mnew);

        float psum = 0.f;
        unsigned pw[2][8];
        #pragma unroll
        for (int sb = 0; sb < 2; ++sb) {
            #pragma unroll
            for (int r2 = 0; r2 < 8; ++r2) {
                float p0 = __expf(sacc[sb][2 * r2]     - mnew);
                float p1 = __expf(sacc[sb][2 * r2 + 1] - mnew);
                psum += p0 + p1;
                pw[sb][r2] = (unsigned)f2bf(p0) | ((unsigned)f2bf(p1) << 16);
            }
        }
        psum += __shfl_xor(psum, 32);
        l_run = l_run * alpha + psum;
        m_run = mnew;
        #pragma unroll
        for (int dt = 0; dt < 2; ++dt)
            #pragma unroll
            for (int r = 0; r < 16; ++r)
                oacc[dt][r] *= alpha;

        // ---- build P^T B-frags: half-exchange via shfl_xor(32) ----
        unsigned px[2][8];
        #pragma unroll
        for (int sb = 0; sb < 2; ++sb)
            #pragma unroll
            for (int i = 0; i < 8; ++i)
                px[sb][i] = __shfl_xor(pw[sb][i], 32);

        bf16x8 pfrag[4];
        #pragma unroll
        for (int sb = 0; sb < 2; ++sb) {
            #pragma unroll
            for (int c = 0; c < 2; ++c) {
                unsigned u0, u1, u2, u3;
                if (h == 0) { u0 = pw[sb][4*c];   u1 = pw[sb][4*c+1]; u2 = px[sb][4*c];   u3 = px[sb][4*c+1]; }
                else        { u0 = px[sb][4*c+2]; u1 = px[sb][4*c+3]; u2 = pw[sb][4*c+2]; u3 = pw[sb][4*c+3]; }
                union { unsigned u[4]; bf16x8 v; } cvt;
                cvt.u[0] = u0; cvt.u[1] = u1; cvt.u[2] = u2; cvt.u[3] = u3;
                pfrag[sb * 2 + c] = cvt.v;
            }
        }

        // ---- PV: O^T[d][q] += V^T x P^T ----
        #pragma unroll
        for (int dt = 0; dt < 2; ++dt)
            #pragma unroll
            for (int sc = 0; sc < 4; ++sc)
                oacc[dt] = __builtin_amdgcn_mfma_f32_32x32x16_bf16(
                    vtf[(dt * 4 + sc) * 64 + lane], pfrag[sc], oacc[dt], 0, 0, 0);
    }

    // ---- epilogue: normalize, write AO[b, t, head*64 + d] ----
    const float inv = 1.0f / l_run;
    float* aop = AO + ((size_t)(bh >> 4) * SEQL + qglob) * NEMB + (bh & 15) * HD;
    #pragma unroll
    for (int dt = 0; dt < 2; ++dt) {
        #pragma unroll
        for (int rg = 0; rg < 4; ++rg) {
            int d0 = dt * 32 + rg * 8 + h * 4;
            float4 o4;
            o4.x = oacc[dt][rg * 4 + 0] * inv;
            o4.y = oacc[dt][rg * 4 + 1] * inv;
            o4.z = oacc[dt][rg * 4 + 2] * inv;
            o4.w = oacc[dt][rg * 4 + 3] * inv;
            *(float4*)(aop + d0) = o4;
        }
    }
}

// ---------------------------------------------------------------------------
// Kernel 3: output projection + bias (fp32 VALU GEMM, unchanged).
// ---------------------------------------------------------------------------
__global__ __launch_bounds__(256) void out_proj_kernel(
    const float* __restrict__ A,
    const float* __restrict__ Wp,
    const float* __restrict__ bp,
    float* __restrict__ out)
{
    const int m0 = blockIdx.x * 128;
    const int n0 = blockIdx.y * 128;

    __shared__ float a_t[16][132];
    __shared__ float b_s[16][132];

    const int tid = threadIdx.x;
    const int ty = tid >> 4, tx = tid & 15;

    float acc[8][8] = {};

    for (int k0 = 0; k0 < NEMB; k0 += 16) {
        #pragma unroll
        for (int q = 0; q < 2; ++q) {
            int fidx = q * 256 + tid;
            int row  = fidx >> 2;
            int kq   = fidx & 3;
            float4 v = *(const float4*)(A + (m0 + row) * NEMB + k0 + kq * 4);
            a_t[kq*4+0][row] = v.x;
            a_t[kq*4+1][row] = v.y;
            a_t[kq*4+2][row] = v.z;
            a_t[kq*4+3][row] = v.w;
        }
        #pragma unroll
        for (int q = 0; q < 2; ++q) {
            int fidx = q * 256 + tid;
            int kk = fidx >> 5;
            int nn = (fidx & 31) * 4;
            float4 v = *(const float4*)(Wp + (k0 + kk) * NEMB + n0 + nn);
            *(float4*)(&b_s[kk][nn]) = v;
        }
        __syncthreads();
        #pragma unroll
        for (int kk = 0; kk < 16; ++kk) {
            float a[8], b[8];
            *(float4*)&a[0] = *(const float4*)&a_t[kk][ty * 4];
            *(float4*)&a[4] = *(const float4*)&a_t[kk][64 + ty * 4];
            *(float4*)&b[0] = *(const float4*)&b_s[kk][tx * 4];
            *(float4*)&b[4] = *(const float4*)&b_s[kk][64 + tx * 4];
            #pragma unroll
            for (int i = 0; i < 8; ++i)
                #pragma unroll
                for (int j = 0; j < 8; ++j)
                    acc[i][j] = fmaf(a[i], b[j], acc[i][j]);
        }
        __syncthreads();
    }

    float4 bias[2];
    bias[0] = *(const float4*)(bp + n0 + tx * 4);
    bias[1] = *(const float4*)(bp + n0 + 64 + tx * 4);

    #pragma unroll
    for (int ih = 0; ih < 2; ++ih) {
        #pragma unroll
        for (int i2 = 0; i2 < 4; ++i2) {
            int i = ih * 4 + i2;
            int m = m0 + ih * 64 + ty * 4 + i2;
            #pragma unroll
            for (int jh = 0; jh < 2; ++jh) {
                float4 r;
                r.x = acc[i][jh*4+0] + ((const float*)&bias[jh])[0];
                r.y = acc[i][jh*4+1] + ((const float*)&bias[jh])[1];
                r.z = acc[i][jh*4+2] + ((const float*)&bias[jh])[2];
                r.w = acc[i][jh*4+3] + ((const float*)&bias[jh])[3];
                *(float4*)(out + (size_t)m * NEMB + n0 + jh * 64 + tx * 4) = r;
            }
        }
    }
}

// ---------------------------------------------------------------------------
extern "C" void kernel_launch(void* const* d_in, const int* in_sizes, int n_in,
                              void* d_out, int out_size, void* d_ws, size_t ws_size,
                              hipStream_t stream)
{
    const float* ix = (const float*)d_in[0];
    const float* Wq = (const float*)d_in[1];
    const float* Wk = (const float*)d_in[2];
    const float* Wv = (const float*)d_in[3];
    const float* Wp = (const float*)d_in[4];
    const float* bp = (const float*)d_in[5];
    float* out = (float*)d_out;

    const size_t NQ = (size_t)BATCH * NH * SEQL * HD;
    float* Qw = (float*)d_ws;
    float* Kw = Qw + NQ;
    float* Vw = Kw + NQ;
    float* AO = Vw + NQ;

    dim3 g1(MROWS / 128, NEMB / 128, 3);
    qkv_proj_kernel<<<g1, 256, 0, stream>>>(ix, Wq, Wk, Wv, Qw, Kw, Vw);

    attn_mfma_kernel<<<512, 256, 0, stream>>>(Qw, Kw, Vw, AO);

    dim3 g3(MROWS / 128, NEMB / 128);
    out_proj_kernel<<<g3, 256, 0, stream>>>(AO, Wp, bp, out);
}

// Round 3
// 292.031 us; speedup vs baseline: 3.2880x; 2.0217x over previous
//
#include <hip/hip_runtime.h>

#define BATCH 2
#define SEQL  2048
#define NEMB  1024
#define NH    16
#define HD    64
#define MROWS (BATCH*SEQL)   // 4096

typedef short bf16x8 __attribute__((ext_vector_type(8)));
typedef float f32x16 __attribute__((ext_vector_type(16)));

// round-to-nearest-even float -> bf16 bits
__device__ __forceinline__ unsigned short f2bf(float x) {
    union { float f; unsigned u; } v; v.f = x;
    unsigned r = v.u + 0x7FFFu + ((v.u >> 16) & 1u);
    return (unsigned short)(r >> 16);
}
__device__ __forceinline__ void split_bf16(float x, unsigned short& hi, unsigned short& lo) {
    hi = f2bf(x);
    union { unsigned u; float f; } h; h.u = ((unsigned)hi) << 16;
    lo = f2bf(x - h.f);
}

// ---------------------------------------------------------------------------
// Conversion pass 1: ix (fp32) -> ix_hi, ix_lo (bf16), row-major [m][c].
// ---------------------------------------------------------------------------
__global__ __launch_bounds__(256) void split_convert_kernel(
    const float* __restrict__ src,
    unsigned short* __restrict__ dhi, unsigned short* __restrict__ dlo)
{
    int i = (blockIdx.x * 256 + threadIdx.x) * 4;
    float4 v = *(const float4*)(src + i);
    unsigned short h[4], l[4];
    split_bf16(v.x, h[0], l[0]); split_bf16(v.y, h[1], l[1]);
    split_bf16(v.z, h[2], l[2]); split_bf16(v.w, h[3], l[3]);
    uint2 ph, pl;
    ph.x = h[0] | ((unsigned)h[1] << 16); ph.y = h[2] | ((unsigned)h[3] << 16);
    pl.x = l[0] | ((unsigned)l[1] << 16); pl.y = l[2] | ((unsigned)l[3] << 16);
    *(uint2*)(dhi + i) = ph;
    *(uint2*)(dlo + i) = pl;
}

// ---------------------------------------------------------------------------
// Conversion pass 2: transpose + convert weights so GEMM B-staging reads
// 8 consecutive k at fixed n.  z=0: Wq->hi/lo, z=1: Wk->hi/lo, z=2: Wv->hi,
// z=3: Wp->hi.  W[h][c][d] (rstride 64) / Wp[c][n] (rstride 1024) -> Wt[n][c].
// ---------------------------------------------------------------------------
__global__ __launch_bounds__(256) void transpose_convert_kernel(
    const float* __restrict__ Wq, const float* __restrict__ Wk,
    const float* __restrict__ Wv, const float* __restrict__ Wp,
    unsigned short* __restrict__ qhi, unsigned short* __restrict__ qlo,
    unsigned short* __restrict__ khi, unsigned short* __restrict__ klo,
    unsigned short* __restrict__ vhi, unsigned short* __restrict__ pt)
{
    __shared__ float tile[64][68];
    const int z = blockIdx.z, hb = blockIdx.y, c0 = blockIdx.x * 64;
    const float* src; int rstride; unsigned short* dhi; unsigned short* dlo;
    if (z == 0)      { src = Wq + (size_t)hb * 65536; rstride = 64;   dhi = qhi; dlo = qlo; }
    else if (z == 1) { src = Wk + (size_t)hb * 65536; rstride = 64;   dhi = khi; dlo = klo; }
    else if (z == 2) { src = Wv + (size_t)hb * 65536; rstride = 64;   dhi = vhi; dlo = nullptr; }
    else             { src = Wp + (size_t)hb * 64;    rstride = 1024; dhi = pt;  dlo = nullptr; }
    const int tid = threadIdx.x;
    #pragma unroll
    for (int i = 0; i < 4; ++i) {
        int fidx = i * 256 + tid;
        int r  = fidx >> 4;
        int dq = (fidx & 15) * 4;
        float4 v = *(const float4*)(src + (size_t)(c0 + r) * rstride + dq);
        *(float4*)&tile[r][dq] = v;
    }
    __syncthreads();
    #pragma unroll
    for (int i = 0; i < 4; ++i) {
        int fidx = i * 256 + tid;
        int d  = fidx >> 4;
        int cq = (fidx & 15) * 4;
        size_t base = (size_t)(hb * 64 + d) * 1024 + c0 + cq;
        unsigned short hh[4], ll[4];
        #pragma unroll
        for (int j = 0; j < 4; ++j) split_bf16(tile[cq + j][d], hh[j], ll[j]);
        uint2 ph; ph.x = hh[0] | ((unsigned)hh[1] << 16); ph.y = hh[2] | ((unsigned)hh[3] << 16);
        *(uint2*)(dhi + base) = ph;
        if (dlo) {
            uint2 pl; pl.x = ll[0] | ((unsigned)ll[1] << 16); pl.y = ll[2] | ((unsigned)ll[3] << 16);
            *(uint2*)(dlo + base) = pl;
        }
    }
}

// ---------------------------------------------------------------------------
// MFMA GEMM: C[m][n] = A[m][:] . B[n][:]  (both operands k-fast, bf16)
// M=4096, N=1024, K=1024.  BM=BN=128, BK=32, 4 waves (2x2), 64x64 per wave,
// 2x2 MFMA tiles of 32x32x16.  Fragment-linear LDS (conflict-free b128).
// MODE 0: split A/B (3 MFMA), out = hi/lo bf16 in [b,h,t,d]   (Q, K proj)
// MODE 1: plain    (1 MFMA), out = bf16 in [b,h,t,d]          (V proj)
// MODE 2: plain    (1 MFMA), out = fp32 [m][n] + bias         (out proj)
// ---------------------------------------------------------------------------
template<int MODE>
__global__ __launch_bounds__(256) void mfma_gemm(
    const unsigned short* __restrict__ Ahi, const unsigned short* __restrict__ Alo,
    const unsigned short* __restrict__ Bhi, const unsigned short* __restrict__ Blo,
    unsigned short* __restrict__ Ohi, unsigned short* __restrict__ Olo,
    float* __restrict__ Of, const float* __restrict__ bias)
{
    __shared__ unsigned short smem[MODE == 0 ? 16384 : 8192];
    unsigned short* a_hi = smem;
    unsigned short* b_hi = smem + 4096;

    const int m0 = blockIdx.x * 128;
    const int n0 = blockIdx.y * 128;
    const int tid  = threadIdx.x;
    const int wid  = tid >> 6, lane = tid & 63;
    const int wr   = wid >> 1, wc = wid & 1;

    f32x16 acc[2][2] = {};

    for (int kk0 = 0; kk0 < NEMB; kk0 += 32) {
        __syncthreads();
        #pragma unroll
        for (int q = 0; q < 2; ++q) {
            int fidx = q * 256 + tid;
            int row  = fidx >> 2;          // 0..127
            int k8   = (fidx & 3) * 8;     // 0,8,16,24
            int slot = (((row >> 5) * 2 + (k8 >> 4)) * 64 + (row & 31) + 32 * ((k8 >> 3) & 1)) * 8;
            *(bf16x8*)(a_hi + slot) = *(const bf16x8*)(Ahi + (size_t)(m0 + row) * 1024 + kk0 + k8);
            *(bf16x8*)(b_hi + slot) = *(const bf16x8*)(Bhi + (size_t)(n0 + row) * 1024 + kk0 + k8);
            if constexpr (MODE == 0) {
                *(bf16x8*)(smem + 8192  + slot) = *(const bf16x8*)(Alo + (size_t)(m0 + row) * 1024 + kk0 + k8);
                *(bf16x8*)(smem + 12288 + slot) = *(const bf16x8*)(Blo + (size_t)(n0 + row) * 1024 + kk0 + k8);
            }
        }
        __syncthreads();
        #pragma unroll
        for (int kch = 0; kch < 2; ++kch) {
            bf16x8 ah[2], bh_[2];
            #pragma unroll
            for (int mt = 0; mt < 2; ++mt)
                ah[mt] = *(const bf16x8*)(a_hi + (((2 * wr + mt) * 2 + kch) * 64 + lane) * 8);
            #pragma unroll
            for (int nt = 0; nt < 2; ++nt)
                bh_[nt] = *(const bf16x8*)(b_hi + (((2 * wc + nt) * 2 + kch) * 64 + lane) * 8);
            if constexpr (MODE == 0) {
                bf16x8 al[2], bl[2];
                #pragma unroll
                for (int mt = 0; mt < 2; ++mt)
                    al[mt] = *(const bf16x8*)(smem + 8192 + (((2 * wr + mt) * 2 + kch) * 64 + lane) * 8);
                #pragma unroll
                for (int nt = 0; nt < 2; ++nt)
                    bl[nt] = *(const bf16x8*)(smem + 12288 + (((2 * wc + nt) * 2 + kch) * 64 + lane) * 8);
                #pragma unroll
                for (int mt = 0; mt < 2; ++mt)
                    #pragma unroll
                    for (int nt = 0; nt < 2; ++nt) {
                        acc[mt][nt] = __builtin_amdgcn_mfma_f32_32x32x16_bf16(ah[mt], bh_[nt], acc[mt][nt], 0, 0, 0);
                        acc[mt][nt] = __builtin_amdgcn_mfma_f32_32x32x16_bf16(ah[mt], bl[nt],  acc[mt][nt], 0, 0, 0);
                        acc[mt][nt] = __builtin_amdgcn_mfma_f32_32x32x16_bf16(al[mt], bh_[nt], acc[mt][nt], 0, 0, 0);
                    }
            } else {
                #pragma unroll
                for (int mt = 0; mt < 2; ++mt)
                    #pragma unroll
                    for (int nt = 0; nt < 2; ++nt)
                        acc[mt][nt] = __builtin_amdgcn_mfma_f32_32x32x16_bf16(ah[mt], bh_[nt], acc[mt][nt], 0, 0, 0);
            }
        }
    }

    // epilogue
    #pragma unroll
    for (int mt = 0; mt < 2; ++mt) {
        #pragma unroll
        for (int nt = 0; nt < 2; ++nt) {
            const int ncol = n0 + wc * 64 + nt * 32 + (lane & 31);
            if constexpr (MODE == 2) {
                const float bv = bias[ncol];
                #pragma unroll
                for (int r = 0; r < 16; ++r) {
                    int mrow = m0 + wr * 64 + mt * 32 + (r & 3) + 8 * (r >> 2) + 4 * (lane >> 5);
                    Of[(size_t)mrow * 1024 + ncol] = acc[mt][nt][r] + bv;
                }
            } else {
                const int head = ncol >> 6, d = ncol & 63;
                #pragma unroll
                for (int r = 0; r < 16; ++r) {
                    int mrow = m0 + wr * 64 + mt * 32 + (r & 3) + 8 * (r >> 2) + 4 * (lane >> 5);
                    int bb = mrow >> 11, t = mrow & (SEQL - 1);
                    size_t idx = ((size_t)(bb * NH + head) * SEQL + t) * HD + d;
                    float v = acc[mt][nt][r];
                    unsigned short hi = f2bf(v);
                    Ohi[idx] = hi;
                    if constexpr (MODE == 0) {
                        union { unsigned u; float f; } hf; hf.u = ((unsigned)hi) << 16;
                        Olo[idx] = f2bf(v - hf.f);
                    }
                }
            }
        }
    }
}

// ---------------------------------------------------------------------------
// Causal flash attention via MFMA (32x32x16 bf16).  Inputs pre-split bf16.
// Same structure as round 2, staging is now pure bf16x8 -> ds_write (no VALU
// conversion).  Output AO written as bf16 (feeds the bf16 out-proj GEMM).
// ---------------------------------------------------------------------------
__global__ __launch_bounds__(256) void attn_mfma_kernel(
    const unsigned short* __restrict__ Qhi, const unsigned short* __restrict__ Qlo,
    const unsigned short* __restrict__ Khi, const unsigned short* __restrict__ Klo,
    const unsigned short* __restrict__ V,
    unsigned short* __restrict__ AO)
{
    __shared__ unsigned short khi_s[4096];   // [sblk2][chunk4][lane64][8]
    __shared__ unsigned short klo_s[4096];
    __shared__ unsigned short vt_s [4096];   // [dtile2][schunk4][lane64][8]

    const int bid  = blockIdx.x;                 // 0..511
    const int swz  = (bid & 7) * 64 + (bid >> 3);
    const int bh   = swz >> 4;
    const int rb   = 15 - (swz & 15);

    const int tid  = threadIdx.x;
    const int wid  = tid >> 6;
    const int lane = tid & 63;
    const int ln   = lane & 31;
    const int h    = lane >> 5;

    const int qb    = rb * 128 + wid * 32;
    const int qglob = qb + ln;

    const unsigned short* __restrict__ Qbh = Qhi + (size_t)bh * SEQL * HD;
    const unsigned short* __restrict__ Qbl = Qlo + (size_t)bh * SEQL * HD;
    const unsigned short* __restrict__ Kbh = Khi + (size_t)bh * SEQL * HD;
    const unsigned short* __restrict__ Kbl = Klo + (size_t)bh * SEQL * HD;
    const unsigned short* __restrict__ Vb  = V   + (size_t)bh * SEQL * HD;

    bf16x8 qhi[4], qlo[4];
    #pragma unroll
    for (int c = 0; c < 4; ++c) {
        qhi[c] = *(const bf16x8*)(Qbh + (size_t)qglob * HD + c * 16 + h * 8);
        qlo[c] = *(const bf16x8*)(Qbl + (size_t)qglob * HD + c * 16 + h * 8);
    }

    f32x16 oacc[2] = {};
    float m_run = -1e30f, l_run = 0.f;

    const int ntiles    = 2 * (rb + 1);
    const int wave_qmax = qb + 31;

    for (int t = 0; t < ntiles; ++t) {
        const int s0 = t * 64;

        __syncthreads();
        // ---- stage K hi/lo (fragment-linear) and V^T ----
        #pragma unroll
        for (int qq = 0; qq < 2; ++qq) {
            int fidx = qq * 256 + tid;          // 0..511 bf16x8 chunks
            int s  = fidx >> 3;                 // 0..63
            int d0 = (fidx & 7) * 8;            // 0..56
            int ebase = (((s >> 5) * 4 + (d0 >> 4)) * 64 + (s & 31) + 32 * ((d0 >> 3) & 1)) * 8;
            *(bf16x8*)(khi_s + ebase) = *(const bf16x8*)(Kbh + (size_t)(s0 + s) * HD + d0);
            *(bf16x8*)(klo_s + ebase) = *(const bf16x8*)(Kbl + (size_t)(s0 + s) * HD + d0);
            bf16x8 vv = *(const bf16x8*)(Vb + (size_t)(s0 + s) * HD + d0);
            int vbase = ((((d0 >> 5) * 4 + (s >> 4)) * 64) * 8) + (s & 7);
            int lv0   = (d0 & 31) + 32 * ((s >> 3) & 1);
            #pragma unroll
            for (int j = 0; j < 8; ++j)
                vt_s[vbase + (lv0 + j) * 8] = (unsigned short)vv[j];
        }
        __syncthreads();

        if (s0 > wave_qmax) continue;

        const bf16x8* khf = (const bf16x8*)khi_s;
        const bf16x8* klf = (const bf16x8*)klo_s;
        const bf16x8* vtf = (const bf16x8*)vt_s;

        // ---- QK^T (split bf16, 3 MFMA per 16-d chunk) ----
        f32x16 sacc[2] = {};
        #pragma unroll
        for (int sb = 0; sb < 2; ++sb) {
            #pragma unroll
            for (int c = 0; c < 4; ++c) {
                bf16x8 ah = khf[(sb * 4 + c) * 64 + lane];
                bf16x8 al = klf[(sb * 4 + c) * 64 + lane];
                sacc[sb] = __builtin_amdgcn_mfma_f32_32x32x16_bf16(ah, qhi[c], sacc[sb], 0, 0, 0);
                sacc[sb] = __builtin_amdgcn_mfma_f32_32x32x16_bf16(ah, qlo[c], sacc[sb], 0, 0, 0);
                sacc[sb] = __builtin_amdgcn_mfma_f32_32x32x16_bf16(al, qhi[c], sacc[sb], 0, 0, 0);
            }
        }

        // ---- scale *32, causal mask, online softmax ----
        const bool diag = (s0 + 63) > qb;
        float mtile = -1e30f;
        #pragma unroll
        for (int sb = 0; sb < 2; ++sb) {
            #pragma unroll
            for (int r = 0; r < 16; ++r) {
                int srow = (r & 3) + 8 * (r >> 2) + 4 * h + sb * 32;
                float x = sacc[sb][r] * 32.0f;
                if (diag && (s0 + srow) > qglob) x = -1e30f;
                sacc[sb][r] = x;
                mtile = fmaxf(mtile, x);
            }
        }
        mtile = fmaxf(mtile, __shfl_xor(mtile, 32));
        const float mnew  = fmaxf(m_run, mtile);
        const float alpha = __expf(m_run - mnew);

        float psum = 0.f;
        unsigned pw[2][8];
        #pragma unroll
        for (int sb = 0; sb < 2; ++sb) {
            #pragma unroll
            for (int r2 = 0; r2 < 8; ++r2) {
                float p0 = __expf(sacc[sb][2 * r2]     - mnew);
                float p1 = __expf(sacc[sb][2 * r2 + 1] - mnew);
                psum += p0 + p1;
                pw[sb][r2] = (unsigned)f2bf(p0) | ((unsigned)f2bf(p1) << 16);
            }
        }
        psum += __shfl_xor(psum, 32);
        l_run = l_run * alpha + psum;
        m_run = mnew;
        #pragma unroll
        for (int dt = 0; dt < 2; ++dt)
            #pragma unroll
            for (int r = 0; r < 16; ++r)
                oacc[dt][r] *= alpha;

        // ---- build P^T B-frags: half-exchange via shfl_xor(32) ----
        unsigned px[2][8];
        #pragma unroll
        for (int sb = 0; sb < 2; ++sb)
            #pragma unroll
            for (int i = 0; i < 8; ++i)
                px[sb][i] = __shfl_xor(pw[sb][i], 32);

        bf16x8 pfrag[4];
        #pragma unroll
        for (int sb = 0; sb < 2; ++sb) {
            #pragma unroll
            for (int c = 0; c < 2; ++c) {
                unsigned u0, u1, u2, u3;
                if (h == 0) { u0 = pw[sb][4*c];   u1 = pw[sb][4*c+1]; u2 = px[sb][4*c];   u3 = px[sb][4*c+1]; }
                else        { u0 = px[sb][4*c+2]; u1 = px[sb][4*c+3]; u2 = pw[sb][4*c+2]; u3 = pw[sb][4*c+3]; }
                union { unsigned u[4]; bf16x8 v; } cvt;
                cvt.u[0] = u0; cvt.u[1] = u1; cvt.u[2] = u2; cvt.u[3] = u3;
                pfrag[sb * 2 + c] = cvt.v;
            }
        }

        // ---- PV: O^T[d][q] += V^T x P^T ----
        #pragma unroll
        for (int dt = 0; dt < 2; ++dt)
            #pragma unroll
            for (int sc = 0; sc < 4; ++sc)
                oacc[dt] = __builtin_amdgcn_mfma_f32_32x32x16_bf16(
                    vtf[(dt * 4 + sc) * 64 + lane], pfrag[sc], oacc[dt], 0, 0, 0);
    }

    // ---- epilogue: normalize, write AO bf16 [b*T+t][h*64+d] ----
    const float inv = 1.0f / l_run;
    unsigned short* aop = AO + ((size_t)(bh >> 4) * SEQL + qglob) * NEMB + (bh & 15) * HD;
    #pragma unroll
    for (int dt = 0; dt < 2; ++dt) {
        #pragma unroll
        for (int rg = 0; rg < 4; ++rg) {
            int d0 = dt * 32 + rg * 8 + h * 4;
            unsigned short b0 = f2bf(oacc[dt][rg * 4 + 0] * inv);
            unsigned short b1 = f2bf(oacc[dt][rg * 4 + 1] * inv);
            unsigned short b2 = f2bf(oacc[dt][rg * 4 + 2] * inv);
            unsigned short b3 = f2bf(oacc[dt][rg * 4 + 3] * inv);
            uint2 w;
            w.x = (unsigned)b0 | ((unsigned)b1 << 16);
            w.y = (unsigned)b2 | ((unsigned)b3 << 16);
            *(uint2*)(aop + d0) = w;
        }
    }
}

// ---------------------------------------------------------------------------
extern "C" void kernel_launch(void* const* d_in, const int* in_sizes, int n_in,
                              void* d_out, int out_size, void* d_ws, size_t ws_size,
                              hipStream_t stream)
{
    const float* ix = (const float*)d_in[0];
    const float* Wq = (const float*)d_in[1];
    const float* Wk = (const float*)d_in[2];
    const float* Wv = (const float*)d_in[3];
    const float* Wp = (const float*)d_in[4];
    const float* bp = (const float*)d_in[5];
    float* out = (float*)d_out;

    char* ws = (char*)d_ws;
    #define WSOFF(mb) ((unsigned short*)(ws + (size_t)(mb) * 1024 * 1024))
    unsigned short* ix_hi  = WSOFF(0);    // dead after V-GEMM
    unsigned short* ix_lo  = WSOFF(8);
    unsigned short* Wqt_hi = WSOFF(16);   // dead after Q-GEMM
    unsigned short* Wqt_lo = WSOFF(18);
    unsigned short* Wkt_hi = WSOFF(20);   // dead after K-GEMM
    unsigned short* Wkt_lo = WSOFF(22);
    unsigned short* Wvt_hi = WSOFF(24);
    unsigned short* Qhi    = WSOFF(26);
    unsigned short* Qlo    = WSOFF(34);
    unsigned short* Khi    = WSOFF(42);
    unsigned short* Klo    = WSOFF(50);
    unsigned short* Wpt    = WSOFF(58);   // peak usage: 60 MB
    unsigned short* Vbf    = WSOFF(16);   // aliases Wqt/Wkt (dead by then)
    unsigned short* AObf   = WSOFF(0);    // aliases ix_hi (dead by then)
    #undef WSOFF

    // 1. split-convert ix
    split_convert_kernel<<<MROWS * NEMB / 4 / 256, 256, 0, stream>>>(ix, ix_hi, ix_lo);
    // 2. transpose+convert all weights
    transpose_convert_kernel<<<dim3(16, 16, 4), 256, 0, stream>>>(
        Wq, Wk, Wv, Wp, Wqt_hi, Wqt_lo, Wkt_hi, Wkt_lo, Wvt_hi, Wpt);
    // 3-5. projections (MFMA)
    dim3 gg(MROWS / 128, NEMB / 128);
    mfma_gemm<0><<<gg, 256, 0, stream>>>(ix_hi, ix_lo, Wqt_hi, Wqt_lo, Qhi, Qlo, nullptr, nullptr);
    mfma_gemm<0><<<gg, 256, 0, stream>>>(ix_hi, ix_lo, Wkt_hi, Wkt_lo, Khi, Klo, nullptr, nullptr);
    mfma_gemm<1><<<gg, 256, 0, stream>>>(ix_hi, nullptr, Wvt_hi, nullptr, Vbf, nullptr, nullptr, nullptr);
    // 6. attention
    attn_mfma_kernel<<<512, 256, 0, stream>>>(Qhi, Qlo, Khi, Klo, Vbf, AObf);
    // 7. output projection + bias
    mfma_gemm<2><<<gg, 256, 0, stream>>>(AObf, nullptr, Wpt, nullptr, nullptr, nullptr, out, bp);
}